// Round 3
// baseline (306.579 us; speedup 1.0000x reference)
//
#include <hip/hip_runtime.h>

// TaylorExp feature map, d=16:
//   out[row, 0]             = 1
//   out[row, 1..16]         = x[row, i] * 0.5
//   out[row, 17 + i*16 + j] = (x[row,i]*x[row,j]) * (1/(4*sqrt(2)))
//
// v3: persistent-grid version. v1 (divides) == v2 (clean compute) at ~105us
// against a ~50us BW floor => the limiter is structural: 16384 short blocks
// with __syncthreads (vmcnt(0) drain) sawtooth the store pipe and the CU
// refill bubbles are globally synchronized. v3 uses 2048 persistent blocks
// (8/CU, LDS-bound occupancy unchanged), each streaming 8 contiguous tiles:
//   - next tile's x prefetched into registers at loop top (1 tile of cover)
//   - raw "s_waitcnt lgkmcnt(0); s_barrier" (memory-clobbered asm) instead of
//     __syncthreads => global stores stay in flight across tile boundaries.

#define D               16
#define OUTD            273          // 1 + 16 + 256
#define ROWS_PER_BLOCK  16
#define THREADS         256
#define CHUNK           (OUTD * ROWS_PER_BLOCK)   // 4368 floats per tile
#define CHUNK4          (CHUNK / 4)               // 1092 float4 per tile
#define NBLOCKS         2048                      // 8 blocks/CU x 256 CU

#define LDS_BARRIER() asm volatile("s_waitcnt lgkmcnt(0)\n\ts_barrier" ::: "memory")

__global__ __launch_bounds__(THREADS)
void taylor_exp_kernel(const float* __restrict__ x,
                       float* __restrict__ out,
                       int nrows, int tilesTotal, int tilesPerBlock) {
    __shared__ __align__(16) float xs[ROWS_PER_BLOCK * D];   // 1 KB
    __shared__ __align__(16) float tile[CHUNK];              // 17472 B

    const int tid = threadIdx.x;
    const int localRow = tid >> 4;

    const int tBeg = blockIdx.x * tilesPerBlock;
    int tEnd = tBeg + tilesPerBlock;
    if (tEnd > tilesTotal) tEnd = tilesTotal;
    if (tBeg >= tilesTotal) return;     // whole block exits together

    const long long totalOut = (long long)nrows * OUTD;
    const float S2 = 0.17677669529663688f;  // 1/(4*sqrt(2))

    // ---- prologue: stage tile tBeg's x (one coalesced 1 KB load) ----
    {
        const long long rowBase = (long long)tBeg * ROWS_PER_BLOCK;
        float v = 0.0f;
        if (rowBase + localRow < (long long)nrows) v = x[rowBase * D + tid];
        xs[tid] = v;                     // compiler waits vmcnt for v
    }
    LDS_BARRIER();

    for (int t = tBeg; t < tEnd; ++t) {
        // ---- prefetch next tile's x into a register (use is ~1 tile away) ----
        float vnext = 0.0f;
        if (t + 1 < tEnd) {
            const long long rowBase1 = (long long)(t + 1) * ROWS_PER_BLOCK;
            if (rowBase1 + localRow < (long long)nrows)
                vnext = x[rowBase1 * D + tid];
        }

        // ---- phase 1: compute the 16x273 chunk into LDS ----
        // Thread (row = tid>>4, l = tid&15) owns quad-column jj = (l+15)&15:
        // tile[row, 17 + 16*s + jj] = (x[s]*x[jj])*S2, plus the linear elem,
        // plus (l==0) the leading 1.
        {
            const int row = localRow;
            const int l   = tid & 15;
            const int jj  = (l + 15) & 15;

            const float* __restrict__ xr = &xs[row * D];
            float* __restrict__ tr = &tile[row * OUTD];

            const float xj = xr[jj];
            if (l == 0) tr[0] = 1.0f;
            tr[1 + jj] = xj * 0.5f;

            const float4 a0 = reinterpret_cast<const float4*>(xr)[0];  // broadcast reads
            const float4 a1 = reinterpret_cast<const float4*>(xr)[1];
            const float4 a2 = reinterpret_cast<const float4*>(xr)[2];
            const float4 a3 = reinterpret_cast<const float4*>(xr)[3];
            const float xv[16] = {a0.x, a0.y, a0.z, a0.w,  a1.x, a1.y, a1.z, a1.w,
                                  a2.x, a2.y, a2.z, a2.w,  a3.x, a3.y, a3.z, a3.w};
            float* __restrict__ trq = tr + 17 + jj;
#pragma unroll
            for (int s = 0; s < 16; ++s) {
                // (x_i*x_j)*S2 association matches the v1 bit-exact result.
                trq[16 * s] = (xv[s] * xj) * S2;
            }
        }
        LDS_BARRIER();   // tile complete; this wave's xs reads drained

        // ---- phase 2: stream the contiguous 4368-float chunk to global ----
        {
            const long long outBase = (long long)t * CHUNK;   // 16B-aligned
            const float4* __restrict__ t4 = reinterpret_cast<const float4*>(tile);
            float4* __restrict__ o4 = reinterpret_cast<float4*>(out) + (outBase >> 2);

            if (outBase + CHUNK <= totalOut) {
#pragma unroll
                for (int n = 0; n < 5; ++n) {
                    const int k = tid + n * THREADS;
                    if (n < 4 || k < CHUNK4) {
                        o4[k] = t4[k];          // ds_read_b128 -> dwordx4 store
                    }
                }
            } else {
                // ragged tail tile (only if nrows % ROWS_PER_BLOCK != 0)
                for (int k = tid; k < CHUNK4; k += THREADS) {
                    const long long gi = outBase + 4ll * k;
                    const float4 v = t4[k];
                    const float tmp[4] = {v.x, v.y, v.z, v.w};
#pragma unroll
                    for (int e = 0; e < 4; ++e) {
                        if (gi + e < totalOut) out[gi + e] = tmp[e];
                    }
                }
            }
        }

        // xs rewrite is safe: every wave's phase-1 xs reads drained before the
        // previous barrier. Compiler inserts a counted vmcnt for vnext only;
        // the tile stores stay in flight.
        xs[tid] = vnext;
        LDS_BARRIER();   // this wave's tile ds_reads + xs write drained
    }
}

extern "C" void kernel_launch(void* const* d_in, const int* in_sizes, int n_in,
                              void* d_out, int out_size, void* d_ws, size_t ws_size,
                              hipStream_t stream) {
    const float* x = (const float*)d_in[0];
    float* out = (float*)d_out;

    const int n = in_sizes[0];        // total x elements
    const int nrows = n / D;          // 262144 for the bench shape
    const int tilesTotal = (nrows + ROWS_PER_BLOCK - 1) / ROWS_PER_BLOCK;
    int blocks = NBLOCKS;
    if (blocks > tilesTotal) blocks = tilesTotal;
    const int tilesPerBlock = (tilesTotal + blocks - 1) / blocks;

    taylor_exp_kernel<<<dim3(blocks), dim3(THREADS), 0, stream>>>(
        x, out, nrows, tilesTotal, tilesPerBlock);
}

// Round 4
// 292.475 us; speedup vs baseline: 1.0482x; 1.0482x over previous
//
#include <hip/hip_runtime.h>

// TaylorExp feature map, d=16:
//   out[row, 0]             = 1
//   out[row, 1..16]         = x[row, i] * 0.5
//   out[row, 17 + i*16 + j] = x[row,i]*x[row,j] * (1/(4*sqrt(2)))
//
// v4 = v2 + NONTEMPORAL stores. Evidence so far: v1 (divides), v2 (clean
// compute), v3 (persistent grid) all time identically => per-element cost and
// sync structure are NOT the limiter. Remaining kernel-side lever: the output
// is write-once/never-read, so default L2-allocating stores churn the 32MB L2
// (alloc+evict for 286MB); the 'nt' bit streams them. Single-variable A/B vs v2.

#define D               16
#define OUTD            273          // 1 + 16 + 256
#define ROWS_PER_BLOCK  16
#define THREADS         256
#define CHUNK           (OUTD * ROWS_PER_BLOCK)   // 4368 floats per block
#define CHUNK4          (CHUNK / 4)               // 1092 float4 per block

typedef __attribute__((ext_vector_type(4))) float f32x4;

__global__ __launch_bounds__(THREADS)
void taylor_exp_kernel(const float* __restrict__ x,
                       float* __restrict__ out,
                       int nrows) {
    __shared__ __align__(16) float xs[ROWS_PER_BLOCK * D];   // 1 KB
    __shared__ __align__(16) float tile[CHUNK];              // 17472 B

    const int tid = threadIdx.x;
    const long long rowBase = (long long)blockIdx.x * ROWS_PER_BLOCK;

    // ---- Phase 0: stage 16 rows x 16 floats (one coalesced 1 KB load) ----
    {
        const int localRow = tid >> 4;
        float v = 0.0f;
        if (rowBase + localRow < (long long)nrows) {
            v = x[rowBase * D + tid];
        }
        xs[tid] = v;
    }
    __syncthreads();

    // ---- Phase 1: compute the 16x273 output chunk into LDS ----
    // Thread (row = tid>>4, l = tid&15) owns quad-column jj = (l+15)&15 of its
    // row: tile[row, 17 + 16*s + jj] = x[s]*x[jj]*S2 for s = 0..15, plus the
    // linear element tile[row, 1+jj] = x[jj]*0.5, plus (l==0) the leading 1.
    {
        const int row = tid >> 4;
        const int l   = tid & 15;
        const int jj  = (l + 15) & 15;          // l==0 -> 15, else l-1
        const float S2 = 0.17677669529663688f;  // 1/(4*sqrt(2))

        const float* __restrict__ xr = &xs[row * D];
        float* __restrict__ tr = &tile[row * OUTD];

        const float xj = xr[jj];
        if (l == 0) tr[0] = 1.0f;
        tr[1 + jj] = xj * 0.5f;

        const float xj2 = xj * S2;
        // Row vector via 4 broadcast ds_read_b128 (same addr across the row's 16 lanes).
        const float4 a0 = reinterpret_cast<const float4*>(xr)[0];
        const float4 a1 = reinterpret_cast<const float4*>(xr)[1];
        const float4 a2 = reinterpret_cast<const float4*>(xr)[2];
        const float4 a3 = reinterpret_cast<const float4*>(xr)[3];
        const float xv[16] = {a0.x, a0.y, a0.z, a0.w,  a1.x, a1.y, a1.z, a1.w,
                              a2.x, a2.y, a2.z, a2.w,  a3.x, a3.y, a3.z, a3.w};
        float* __restrict__ trq = tr + 17 + jj;
#pragma unroll
        for (int s = 0; s < 16; ++s) {
            trq[16 * s] = xv[s] * xj2;
        }
    }
    __syncthreads();

    // ---- Phase 2: stream the contiguous 4368-float chunk to global (nt) ----
    const long long outBase = rowBase * OUTD;            // multiple of 4368 -> 16B-aligned
    const long long totalOut = (long long)nrows * OUTD;
    const f32x4* __restrict__ t4 = reinterpret_cast<const f32x4*>(tile);
    f32x4* __restrict__ o4 = reinterpret_cast<f32x4*>(out) + (outBase >> 2);

    if (outBase + CHUNK <= totalOut) {
        // Full block: ds_read_b128 -> nontemporal global_store_dwordx4.
#pragma unroll
        for (int n = 0; n < 5; ++n) {
            const int t = tid + n * THREADS;
            if (n < 4 || t < CHUNK4) {
                __builtin_nontemporal_store(t4[t], o4 + t);
            }
        }
    } else {
        // Ragged tail block (only if nrows % ROWS_PER_BLOCK != 0).
        for (int t = tid; t < CHUNK4; t += THREADS) {
            const long long gi = outBase + 4ll * t;
            const f32x4 v = t4[t];
#pragma unroll
            for (int e = 0; e < 4; ++e) {
                if (gi + e < totalOut) __builtin_nontemporal_store(v[e], out + gi + e);
            }
        }
    }
}

extern "C" void kernel_launch(void* const* d_in, const int* in_sizes, int n_in,
                              void* d_out, int out_size, void* d_ws, size_t ws_size,
                              hipStream_t stream) {
    const float* x = (const float*)d_in[0];
    float* out = (float*)d_out;

    const int n = in_sizes[0];        // total x elements
    const int nrows = n / D;          // 262144 for the bench shape
    const int blocks = (nrows + ROWS_PER_BLOCK - 1) / ROWS_PER_BLOCK;

    taylor_exp_kernel<<<dim3(blocks), dim3(THREADS), 0, stream>>>(x, out, nrows);
}